// Round 6
// baseline (5484.307 us; speedup 1.0000x reference)
//
#include <hip/hip_runtime.h>
#include <hip/hip_bf16.h>
#include <stdint.h>
#include <string.h>

#define HIDDEN 1024
#define FEAT   512
#define PREV   10
#define PRED   20
#define BATCH  1024
#define KTOT   (HIDDEN + FEAT)   // 1536
#define N4H    4096
#define TSTEPS (PREV + PRED)     // 30
#define NBLK   512               // 2 blocks/CU on 256 CUs (co-resident for grid barrier)
#define NTHR   512
#define XSTR_R (TSTEPS * FEAT)   // 15360
#define XSTR_F (PRED * FEAT)     // 10240

typedef __attribute__((ext_vector_type(8))) short short8;
typedef __attribute__((ext_vector_type(4))) float f32x4;
typedef unsigned long long ull;

__device__ __forceinline__ float sigmoidf_(float x) {
  return 1.0f / (1.0f + __expf(-x));
}
__device__ __forceinline__ float tanhf_(float x) {
  return 1.0f - 2.0f / (1.0f + __expf(2.0f * x));
}

// device-coherent (LLC) load/store — bypass the non-coherent L1/L2
__device__ __forceinline__ ull cload(const void* p) {
  return __hip_atomic_load((const ull*)p, __ATOMIC_RELAXED, __HIP_MEMORY_SCOPE_AGENT);
}
__device__ __forceinline__ void cstore(void* p, ull v) {
  __hip_atomic_store((ull*)p, v, __ATOMIC_RELAXED, __HIP_MEMORY_SCOPE_AGENT);
}
__device__ __forceinline__ void cstore4(void* p, unsigned v) {
  __hip_atomic_store((unsigned*)p, v, __ATOMIC_RELAXED, __HIP_MEMORY_SCOPE_AGENT);
}

// ---- pack [Wh;Wx] (fp32, [K,4096] gate-blocked) -> WpT (bf16, [4096,K], gate-interleaved n=4j+g) ----
__global__ void pack_w_kernel(const float* __restrict__ Wx, const float* __restrict__ Wh,
                              __hip_bfloat16* __restrict__ WpT) {
  __shared__ float tile[64][65];
  const int k0 = blockIdx.x * 64, n0 = blockIdx.y * 64;
  const int tid = threadIdx.x;
  const float* src = (k0 < HIDDEN) ? (Wh + (size_t)k0 * N4H) : (Wx + (size_t)(k0 - HIDDEN) * N4H);
  {
    const int jl = tid & 15, g = (tid >> 4) & 3, klb = tid >> 6;
#pragma unroll
    for (int it = 0; it < 16; ++it) {
      int kl = klb + it * 4;
      tile[kl][4 * jl + g] = src[(size_t)kl * N4H + g * HIDDEN + (n0 >> 2) + jl];
    }
  }
  __syncthreads();
  {
    const int kl = tid & 63, nlb = tid >> 6;
#pragma unroll
    for (int it = 0; it < 16; ++it) {
      int nl = nlb + it * 4;
      WpT[(size_t)(n0 + nl) * KTOT + k0 + kl] = __float2bfloat16(tile[kl][nl]);
    }
  }
}

__global__ void pack_bias_kernel(const float* __restrict__ b, float* __restrict__ bp) {
  int n = blockIdx.x * 256 + threadIdx.x;
  if (n < N4H) bp[n] = b[(n & 3) * HIDDEN + (n >> 2)];
}

// ---- convert inputs fp32 -> bf16 ----
__global__ void cvt_x_kernel(const float* __restrict__ xr, const float* __restrict__ xf,
                             __hip_bfloat16* __restrict__ xrb, __hip_bfloat16* __restrict__ xfb) {
  const int NR4 = BATCH * TSTEPS * FEAT / 4;
  const int NF4 = BATCH * PRED * FEAT / 4;
  int i = blockIdx.x * 256 + threadIdx.x;
  float4 v;
  __hip_bfloat16* dst;
  if (i < NR4) {
    v = ((const float4*)xr)[i];
    dst = xrb + (size_t)i * 4;
  } else {
    int j = i - NR4;
    if (j >= NF4) return;
    v = ((const float4*)xf)[j];
    dst = xfb + (size_t)j * 4;
  }
  dst[0] = __float2bfloat16(v.x);
  dst[1] = __float2bfloat16(v.y);
  dst[2] = __float2bfloat16(v.z);
  dst[3] = __float2bfloat16(v.w);
}

// ---- register-fragment GEMM for one step, per wave: M = MB*16 rows x 32 cols ----
// No LDS, no barriers. A from h (coherent 8B loads) or x (plain 16B); B plain 16B
// from L2-resident WpT slice. Software pipeline: A 3-slot, B 2-slot; compiler
// emits per-wave fine-grained s_waitcnt vmcnt(N).
template <int MB>
__device__ __forceinline__ void gemm_step(
    const unsigned short* __restrict__ hcur, int hrow,
    const unsigned short* __restrict__ xb, int xstr,
    const unsigned short* __restrict__ wbase,
    f32x4 (&acc)[MB][2], int lq) {
  short8 Af[3][MB];
  short8 Bf[2][2];
  const int koff0 = lq * 8;

  auto loadA = [&](int kt, int s) {
    const int koff = kt * 32 + koff0;
    if (kt < 32) {
#pragma unroll
      for (int mi = 0; mi < MB; ++mi) {
        const ull* p = (const ull*)(hcur + (size_t)(hrow + mi * 16) * HIDDEN + koff);
        union { short8 v; ull u[2]; } t_;
        t_.u[0] = cload(p);
        t_.u[1] = cload(p + 1);
        Af[s][mi] = t_.v;
      }
    } else {
#pragma unroll
      for (int mi = 0; mi < MB; ++mi)
        Af[s][mi] = *(const short8*)(xb + (size_t)(mi * 16) * xstr + (koff - HIDDEN));
    }
  };
  auto loadB = [&](int kt, int s) {
    const int koff = kt * 32 + koff0;
#pragma unroll
    for (int ni = 0; ni < 2; ++ni)
      Bf[s][ni] = *(const short8*)(wbase + (size_t)(ni * 16) * KTOT + koff);
  };

  loadA(0, 0);
  loadB(0, 0);
  loadA(1, 1);
  loadB(1, 1);
#pragma unroll
  for (int kt = 0; kt < KTOT / 32; ++kt) {
    if (kt + 2 < KTOT / 32) loadA(kt + 2, (kt + 2) % 3);
    if (kt + 1 < KTOT / 32) loadB(kt + 1, (kt + 1) & 1);
    const int sa = kt % 3, sb = kt & 1;
#pragma unroll
    for (int mi = 0; mi < MB; ++mi)
#pragma unroll
      for (int ni = 0; ni < 2; ++ni)
        acc[mi][ni] = __builtin_amdgcn_mfma_f32_16x16x32_bf16(Af[sa][mi], Bf[sb][ni], acc[mi][ni], 0, 0, 0);
  }
}

// ---- epilogue: C-layout -> gate transpose through wave-private LDS (no barriers) ----
template <int MB, bool DO_OUT, bool DO_CSTORE>
__device__ __forceinline__ void epilogue(
    f32x4 (&acc)[MB][2], float* __restrict__ zw, const float* __restrict__ bsh,
    float w2a, float w2b, float* __restrict__ creg,
    unsigned short* __restrict__ hnext, float* __restrict__ cbuf,
    float* __restrict__ accout, float* __restrict__ wbuf,
    int r0, int t, int l, int lm, int lq, int w, int jg0) {
#pragma unroll
  for (int mb = 0; mb < MB; ++mb)
#pragma unroll
    for (int ni = 0; ni < 2; ++ni) {
      f32x4 v = acc[mb][ni];
#pragma unroll
      for (int r = 0; r < 4; ++r)
        zw[(mb * 16 + lq * 4 + r) * 34 + ni * 16 + lm] = v[r];
    }
  const int kout = t - PREV;
  float4 ba = *(const float4*)&bsh[w * 32 + lq * 8];
  float4 bb = *(const float4*)&bsh[w * 32 + lq * 8 + 4];
#pragma unroll
  for (int mb = 0; mb < MB; ++mb) {
    float4 za = *(float4*)&zw[(mb * 16 + lm) * 34 + lq * 8];
    float4 zb2 = *(float4*)&zw[(mb * 16 + lm) * 34 + lq * 8 + 4];
    float gi0 = sigmoidf_(za.x + ba.x), gf0 = sigmoidf_(za.y + ba.y);
    float gg0 = tanhf_(za.z + ba.z), go0 = sigmoidf_(za.w + ba.w);
    float c0 = gf0 * creg[mb * 2] + gi0 * gg0;
    float h0 = go0 * tanhf_(c0);
    creg[mb * 2] = c0;
    float gi1 = sigmoidf_(zb2.x + bb.x), gf1 = sigmoidf_(zb2.y + bb.y);
    float gg1 = tanhf_(zb2.z + bb.z), go1 = sigmoidf_(zb2.w + bb.w);
    float c1 = gf1 * creg[mb * 2 + 1] + gi1 * gg1;
    float h1 = go1 * tanhf_(c1);
    creg[mb * 2 + 1] = c1;
    const int rg = r0 + mb * 16 + lm;
    __hip_bfloat16 hv0 = __float2bfloat16(h0), hv1 = __float2bfloat16(h1);
    unsigned hp = (unsigned)*(unsigned short*)&hv0 | ((unsigned)*(unsigned short*)&hv1 << 16);
    cstore4(&hnext[(size_t)rg * HIDDEN + jg0], hp);
    if (DO_CSTORE) {
      float2 cf = {c0, c1};
      ull cp;
      memcpy(&cp, &cf, 8);
      cstore(&cbuf[(size_t)rg * HIDDEN + jg0], cp);
    }
    if (DO_OUT) {
      float p = h0 * w2a + h1 * w2b;
      p += __shfl_down(p, 32, 64);
      p += __shfl_down(p, 16, 64);
      if (l < 16) wbuf[(mb * 16 + l) * 9 + w] = p;
    }
  }
  if (DO_OUT) {
    __syncthreads();
    const int tid = threadIdx.x;
    if (tid < 16 * MB) {
      float s = 0.f;
#pragma unroll
      for (int ww = 0; ww < 8; ++ww) s += wbuf[tid * 9 + ww];
      atomicAdd(&accout[(size_t)(r0 + tid) * PRED + kout], s);
    }
  }
}

// ---- persistent LSTM: all 30 steps, one cooperative dispatch, barrier-free K-loops ----
// 512 blocks x 512 thr (8 waves). nt = bid&15: block cols 256 (L2-resident weight
// slice, ~1.6 MB/XCD); rt = bid>>4. Wave w owns cols n0b + w*32. Prefix: M=32/wave
// (all blocks active); main: M=64/wave. Cell state in registers; handoff via cbuf.
__global__ __launch_bounds__(512, 4)
void lstm_persistent(const __hip_bfloat16* __restrict__ xrb,
                     const __hip_bfloat16* __restrict__ xfb,
                     const __hip_bfloat16* __restrict__ WpT,
                     const float* __restrict__ biasp,
                     const float* __restrict__ w2,
                     __hip_bfloat16* __restrict__ hb0,
                     __hip_bfloat16* __restrict__ hb1,
                     float* __restrict__ cbuf,
                     float* __restrict__ accout,
                     unsigned* __restrict__ bar) {
  __shared__ float zbuf[8 * 64 * 34];  // wave-private z regions (68 KB)
  __shared__ float bsh[256];           // block bias slice
  __shared__ float wbuf[64 * 9];       // w2-dot block reduce
  const int tid = threadIdx.x;
  const int bid = blockIdx.x;
  const int nt = bid & 15, rt = bid >> 4;
  const int w = tid >> 6, l = tid & 63, lm = l & 15, lq = l >> 4;
  const int n0b = nt * 256, n0w = n0b + w * 32;
  const int jg0 = (n0w >> 2) + lq * 2;
  float* zw = zbuf + w * (64 * 34);
  unsigned* cnt = bar;
  unsigned* flag = bar + 32;

  if (tid < 256) bsh[tid] = biasp[n0b + tid];
  const float w2a = w2[jg0], w2b = w2[jg0 + 1];
  const unsigned short* wbase = (const unsigned short*)WpT + (size_t)(n0w + lm) * KTOT;
  const unsigned short* xr_us = (const unsigned short*)xrb;
  const unsigned short* xf_us = (const unsigned short*)xfb;
  float creg[8] = {0.f, 0.f, 0.f, 0.f, 0.f, 0.f, 0.f, 0.f};
  __syncthreads();

#pragma unroll 1
  for (int t = 0; t < TSTEPS; ++t) {
    const unsigned short* hcur = (const unsigned short*)((t & 1) ? hb1 : hb0);
    unsigned short* hnext = (unsigned short*)((t & 1) ? hb0 : hb1);

    if (t < PREV) {
      const int r0 = rt * 32;
      const unsigned short* xb = xr_us + (size_t)(r0 + lm) * XSTR_R + t * FEAT;
      f32x4 acc[2][2];
#pragma unroll
      for (int a = 0; a < 2; ++a)
        for (int b_ = 0; b_ < 2; ++b_) acc[a][b_] = (f32x4){0.f, 0.f, 0.f, 0.f};
      gemm_step<2>(hcur, r0 + lm, xb, XSTR_R, wbase, acc, lq);
      if (t == PREV - 1)
        epilogue<2, false, true>(acc, zw, bsh, w2a, w2b, creg, hnext, cbuf, accout, wbuf,
                                 r0, t, l, lm, lq, w, jg0);
      else
        epilogue<2, false, false>(acc, zw, bsh, w2a, w2b, creg, hnext, cbuf, accout, wbuf,
                                  r0, t, l, lm, lq, w, jg0);
    } else {
      const int r0 = rt * 64;
      const unsigned short* xb;
      int xstr;
      if (r0 < BATCH) {
        xb = xr_us + (size_t)(r0 + lm) * XSTR_R + t * FEAT;
        xstr = XSTR_R;
      } else {
        xb = xf_us + (size_t)(r0 - BATCH + lm) * XSTR_F + (t - PREV) * FEAT;
        xstr = XSTR_F;
      }
      int r0a = r0;
      if (t == PREV) {
        const int r0c = (r0 >= BATCH) ? r0 - BATCH : r0;
        r0a = r0c;
#pragma unroll
        for (int mb = 0; mb < 4; ++mb) {
          ull cp = cload(&cbuf[(size_t)(r0c + mb * 16 + lm) * HIDDEN + jg0]);
          float2 cf;
          memcpy(&cf, &cp, 8);
          creg[mb * 2] = cf.x;
          creg[mb * 2 + 1] = cf.y;
        }
      }
      f32x4 acc[4][2];
#pragma unroll
      for (int a = 0; a < 4; ++a)
        for (int b_ = 0; b_ < 2; ++b_) acc[a][b_] = (f32x4){0.f, 0.f, 0.f, 0.f};
      gemm_step<4>(hcur, r0a + lm, xb, xstr, wbase, acc, lq);
      epilogue<4, true, false>(acc, zw, bsh, w2a, w2b, creg, hnext, cbuf, accout, wbuf,
                               r0, t, l, lm, lq, w, jg0);
    }

    // ---- grid barrier: relaxed poll, no cache-invalidating fences ----
    if (t < TSTEPS - 1) {
      __syncthreads();  // drains vmcnt (coherent stores reached LLC)
      if (tid == 0) {
        unsigned ph = (unsigned)(t + 1);
        unsigned old = __hip_atomic_fetch_add(cnt, 1u, __ATOMIC_RELAXED, __HIP_MEMORY_SCOPE_AGENT);
        if (old == NBLK - 1) {
          __hip_atomic_store(cnt, 0u, __ATOMIC_RELAXED, __HIP_MEMORY_SCOPE_AGENT);
          __hip_atomic_store(flag, ph, __ATOMIC_RELAXED, __HIP_MEMORY_SCOPE_AGENT);
        } else {
          while (__hip_atomic_load(flag, __ATOMIC_RELAXED, __HIP_MEMORY_SCOPE_AGENT) < ph)
            __builtin_amdgcn_s_sleep(4);
        }
      }
      __syncthreads();
    }
  }
}

// ---- final tanh chain over the 40960 fused dots ----
__global__ void final_kernel(const float* __restrict__ accout, const float* __restrict__ b2,
                             const float* __restrict__ w3, const float* __restrict__ b3,
                             const float* __restrict__ w4, const float* __restrict__ b4,
                             float* __restrict__ out) {
  int i = blockIdx.x * 256 + threadIdx.x;
  const int half = BATCH * PRED;
  if (i >= 2 * half) return;
  int r, k;
  if (i < half) {
    r = i / PRED;
    k = i % PRED;
  } else {
    r = BATCH + (i - half) / PRED;
    k = (i - half) % PRED;
  }
  float x = tanhf_(accout[r * PRED + k] + b2[0]);
  x = tanhf_(x * w3[0] + b3[0]);
  x = tanhf_(x * w4[0] + b4[0]);
  out[i] = x;
}

extern "C" void kernel_launch(void* const* d_in, const int* in_sizes, int n_in,
                              void* d_out, int out_size, void* d_ws, size_t ws_size,
                              hipStream_t stream) {
  const float* real_input = (const float*)d_in[0];
  const float* fake_input = (const float*)d_in[1];
  const float* Wx = (const float*)d_in[2];
  const float* Wh = (const float*)d_in[3];
  const float* b  = (const float*)d_in[4];
  const float* w2 = (const float*)d_in[5];
  const float* b2 = (const float*)d_in[6];
  const float* w3 = (const float*)d_in[7];
  const float* b3 = (const float*)d_in[8];
  const float* w4 = (const float*)d_in[9];
  const float* b4 = (const float*)d_in[10];
  float* out = (float*)d_out;

  char* ws = (char*)d_ws;
  size_t off = 0;
  __hip_bfloat16* WpT = (__hip_bfloat16*)(ws + off);  off += (size_t)N4H * KTOT * 2;
  float* biasp = (float*)(ws + off);                  off += (size_t)N4H * 4;
  __hip_bfloat16* xrb = (__hip_bfloat16*)(ws + off);  off += (size_t)BATCH * TSTEPS * FEAT * 2;
  __hip_bfloat16* xfb = (__hip_bfloat16*)(ws + off);  off += (size_t)BATCH * PRED * FEAT * 2;
  __hip_bfloat16* hb0 = (__hip_bfloat16*)(ws + off);  off += (size_t)2 * BATCH * HIDDEN * 2;
  __hip_bfloat16* hb1 = (__hip_bfloat16*)(ws + off);  off += (size_t)2 * BATCH * HIDDEN * 2;
  float* cbuf = (float*)(ws + off);                   off += (size_t)BATCH * HIDDEN * 4;
  float* accout = (float*)(ws + off);                 off += (size_t)2 * BATCH * PRED * 4;
  unsigned* bar = (unsigned*)(ws + off);              off += 256;

  hipMemsetAsync(hb0, 0, (size_t)2 * BATCH * HIDDEN * 2, stream);
  hipMemsetAsync(accout, 0, (size_t)2 * BATCH * PRED * 4, stream);
  hipMemsetAsync(bar, 0, 256, stream);

  pack_w_kernel<<<dim3(KTOT / 64, N4H / 64), 256, 0, stream>>>(Wx, Wh, WpT);
  pack_bias_kernel<<<N4H / 256, 256, 0, stream>>>(b, biasp);
  {
    int n4 = BATCH * TSTEPS * FEAT / 4 + BATCH * PRED * FEAT / 4;
    cvt_x_kernel<<<(n4 + 255) / 256, 256, 0, stream>>>(real_input, fake_input, xrb, xfb);
  }

  {
    const __hip_bfloat16* a_xrb = xrb;
    const __hip_bfloat16* a_xfb = xfb;
    const __hip_bfloat16* a_WpT = WpT;
    const float* a_biasp = biasp;
    const float* a_w2 = w2;
    __hip_bfloat16* a_hb0 = hb0;
    __hip_bfloat16* a_hb1 = hb1;
    float* a_cbuf = cbuf;
    float* a_acc = accout;
    unsigned* a_bar = bar;
    void* args[10] = {&a_xrb, &a_xfb, &a_WpT, &a_biasp, &a_w2,
                      &a_hb0, &a_hb1, &a_cbuf, &a_acc, &a_bar};
    hipError_t e = hipLaunchCooperativeKernel((const void*)lstm_persistent,
                                              dim3(NBLK), dim3(NTHR), args, 0, stream);
    if (e != hipSuccess) {
      // co-residency by construction: 72 KB LDS + <=128 VGPR -> 2 blocks/CU
      lstm_persistent<<<dim3(NBLK), dim3(NTHR), 0, stream>>>(
          xrb, xfb, WpT, biasp, w2, hb0, hb1, cbuf, accout, bar);
    }
  }

  final_kernel<<<(2 * BATCH * PRED + 255) / 256, 256, 0, stream>>>(accout, b2, w3, b3, w4, b4, out);
}